// Round 1
// baseline (313.628 us; speedup 1.0000x reference)
//
#include <hip/hip_runtime.h>
#include <stdint.h>

typedef __attribute__((ext_vector_type(8))) short bf16x8;
typedef __attribute__((ext_vector_type(4))) float f32x4;

#define DW 147456        // per-member weight elems = 128*128*3*3
#define NTOT (6 * DW)    // U elems

__device__ __forceinline__ unsigned short f2bf(float f) {
    unsigned int u = __float_as_uint(f);
    u = (u + 0x7FFFu + ((u >> 16) & 1u)) >> 16;   // RNE, matches XLA f32->bf16
    return (unsigned short)u;
}

// ---------- 1) min/max reduction over U ----------
__global__ __launch_bounds__(256) void reduce_part(const float* __restrict__ U,
                                                   float* __restrict__ part) {
    int tid = threadIdx.x;
    float mx = -INFINITY, mn = INFINITY;
    for (int i = blockIdx.x * 256 + tid; i < NTOT; i += 256 * 256) {
        float v = U[i];
        mx = fmaxf(mx, v);
        mn = fminf(mn, v);
    }
    __shared__ float smx[256], smn[256];
    smx[tid] = mx; smn[tid] = mn;
    __syncthreads();
    for (int s = 128; s > 0; s >>= 1) {
        if (tid < s) {
            smx[tid] = fmaxf(smx[tid], smx[tid + s]);
            smn[tid] = fminf(smn[tid], smn[tid + s]);
        }
        __syncthreads();
    }
    if (tid == 0) { part[blockIdx.x] = smx[0]; part[256 + blockIdx.x] = smn[0]; }
}

__global__ __launch_bounds__(256) void reduce_final(const float* __restrict__ part,
                                                    float* __restrict__ scal) {
    int tid = threadIdx.x;
    __shared__ float smx[256], smn[256];
    smx[tid] = part[tid]; smn[tid] = part[256 + tid];
    __syncthreads();
    for (int s = 128; s > 0; s >>= 1) {
        if (tid < s) {
            smx[tid] = fmaxf(smx[tid], smx[tid + s]);
            smn[tid] = fminf(smn[tid], smn[tid + s]);
        }
        __syncthreads();
    }
    if (tid == 0) { scal[0] = smx[0]; scal[1] = smn[0]; }
}

// ---------- 2) weight synthesis -> bf16, layout [mem][c][tap][oc][32ch] ----------
__global__ __launch_bounds__(256) void make_weights(const float* __restrict__ U,
                                                    const float* __restrict__ bp,
                                                    const float* __restrict__ uu,
                                                    const float* __restrict__ scal,
                                                    unsigned short* __restrict__ Wb2) {
    int d = blockIdx.x * 256 + threadIdx.x;
    if (d >= DW) return;
    float beta = scal[0], alpha = scal[1];
    float s1 = (beta - alpha) / 3.0f;
    float s2 = s1 / 5.0f;

    float v1[6]; float vsum = 0.f;
    #pragma unroll
    for (int n = 0; n < 6; n++) {
        float Un = U[n * DW + d];
        float v = s1 * rintf(Un / s1);   // rintf = round-half-even = jnp.round
        v1[n] = v; vsum += v;
    }
    float vmean = vsum / 6.0f;

    float g6;
    {
        float un = uu[6 * DW + d];
        float g = logf(un / (1.0f - un));
        float sg = 1.0f / (1.0f + expf(-(g + bp[6 * DW + d])));
        g6 = fminf(fmaxf(sg * 1.4f - 0.2f, 0.0f), 1.0f);
    }

    int oc = d / 1152;
    int rem = d - oc * 1152;
    int ic = rem / 9;
    int t9 = rem - ic * 9;
    int c = ic >> 5, icc = ic & 31;
    size_t base = ((size_t)c * 9 + t9) * 4096 + (size_t)oc * 32 + icc;

    #pragma unroll
    for (int n = 0; n < 6; n++) {
        float un = uu[n * DW + d];
        float g = logf(un / (1.0f - un));
        float sg = 1.0f / (1.0f + expf(-(g + bp[n * DW + d])));
        float g0 = fminf(fmaxf(sg * 1.4f - 0.2f, 0.0f), 1.0f);
        float Un = U[n * DW + d];
        float v2 = s2 * rintf((Un - vmean) / s2);
        // w = v1*g0*(g0>0) + v2*g6*(g0>0)*(g6>0); gates>=0 so g*(g>0)==g
        float w = v1[n] * g0 + ((g0 > 0.0f && g6 > 0.0f) ? v2 * g6 : 0.0f);
        Wb2[(size_t)n * DW + base] = f2bf(w);
    }
}

// ---------- 3) NCHW fp32 -> [img][row][col][ch] bf16 ----------
__global__ __launch_bounds__(256) void transform_x(const float* __restrict__ x,
                                                   unsigned short* __restrict__ xT) {
    __shared__ unsigned short Sh[128 * 70];   // stride 70 (=35 words, odd*? gcd(35,32)=1) spreads banks
    int b = blockIdx.x;
    int img = b >> 6, row = b & 63;
    int tid = threadIdx.x;
    {
        int ch = tid >> 1;
        int col0 = (tid & 1) * 32;
        const float* src = x + (((size_t)(img * 128 + ch) * 64 + row) * 64 + col0);
        #pragma unroll
        for (int j = 0; j < 8; j++) {
            float4 v = ((const float4*)src)[j];
            unsigned int p0 = (unsigned int)f2bf(v.x) | ((unsigned int)f2bf(v.y) << 16);
            unsigned int p1 = (unsigned int)f2bf(v.z) | ((unsigned int)f2bf(v.w) << 16);
            unsigned int* dst = (unsigned int*)&Sh[ch * 70 + col0 + j * 4];
            dst[0] = p0; dst[1] = p1;
        }
    }
    __syncthreads();
    {
        int col = tid & 63;          // lanes = cols -> 2-way LDS read aliasing only (free)
        int chg = (tid >> 6) * 32;   // wave selects channel quarter
        union { unsigned short s[32]; uint4 v[4]; } tmp;
        #pragma unroll
        for (int j = 0; j < 32; j++) tmp.s[j] = Sh[(chg + j) * 70 + col];
        uint4* dst = (uint4*)(xT + (((size_t)(img * 64 + row) * 64 + col) * 128 + chg));
        #pragma unroll
        for (int k = 0; k < 4; k++) dst[k] = tmp.v[k];
    }
}

// ---------- 4) grouped conv via implicit-GEMM MFMA ----------
// block: 128 oc x 128 px (2 rows x 64 cols), K = 9 taps x 128 ic
__global__ __launch_bounds__(256) void conv_mfma(const unsigned short* __restrict__ xT,
                                                 const unsigned short* __restrict__ Wb2,
                                                 float* __restrict__ out) {
    __shared__ __align__(16) unsigned short Xs[4096];  // [px][32k], 64B rows
    __shared__ __align__(16) unsigned short Ws[4096];  // [oc][32k], 64B rows
    int blk = blockIdx.x;
    int img = blk >> 5;
    int row0 = (blk & 31) * 2;
    int mem = img - (img / 6) * 6;
    const unsigned short* Wsrc = Wb2 + (size_t)mem * DW;
    const unsigned short* Xsrc = xT + (size_t)img * 524288;

    int tid = threadIdx.x;
    int lane = tid & 63;
    int wave = tid >> 6;
    int ocbase = (wave & 1) * 64;
    int pxbase = (wave >> 1) * 64;
    int lr = lane & 15, lq = lane >> 4;

    f32x4 acc[4][4];
    #pragma unroll
    for (int mi = 0; mi < 4; mi++)
        #pragma unroll
        for (int ni = 0; ni < 4; ni++)
            acc[mi][ni] = (f32x4){0.f, 0.f, 0.f, 0.f};

    for (int c = 0; c < 4; c++) {
        for (int t = 0; t < 9; t++) {
            int dy = t / 3;
            int dx = t - dy * 3;
            // stage X: 512 x 16B, gather with zero-pad predication; LDS writes contiguous
            #pragma unroll
            for (int ii = 0; ii < 2; ii++) {
                int i = tid + ii * 256;
                int px = i >> 2, cc = i & 3;
                int srow = row0 + (px >> 6) + dy - 1;
                int scol = (px & 63) + dx - 1;
                uint4 v = make_uint4(0u, 0u, 0u, 0u);
                if ((unsigned)srow < 64u && (unsigned)scol < 64u)
                    v = *(const uint4*)(Xsrc + ((srow * 64 + scol) * 128 + c * 32 + cc * 8));
                *(uint4*)(Xs + i * 8) = v;
            }
            // stage W: pure contiguous 8KB copy (pre-swizzled layout)
            const unsigned short* wp = Wsrc + (c * 9 + t) * 4096;
            #pragma unroll
            for (int ii = 0; ii < 2; ii++) {
                int i = tid + ii * 256;
                *(uint4*)(Ws + i * 8) = *(const uint4*)(wp + i * 8);
            }
            __syncthreads();
            bf16x8 af[4], bfr[4];
            #pragma unroll
            for (int mi = 0; mi < 4; mi++)
                af[mi] = *(const bf16x8*)(Ws + (ocbase + mi * 16 + lr) * 32 + lq * 8);
            #pragma unroll
            for (int ni = 0; ni < 4; ni++)
                bfr[ni] = *(const bf16x8*)(Xs + (pxbase + ni * 16 + lr) * 32 + lq * 8);
            #pragma unroll
            for (int mi = 0; mi < 4; mi++)
                #pragma unroll
                for (int ni = 0; ni < 4; ni++)
                    acc[mi][ni] = __builtin_amdgcn_mfma_f32_16x16x32_bf16(
                        af[mi], bfr[ni], acc[mi][ni], 0, 0, 0);
            __syncthreads();
        }
    }
    // epilogue: C/D layout col=lane&15 (=px), row=(lane>>4)*4+reg (=oc)
    float* obase = out + (size_t)img * 524288 + row0 * 64;
    #pragma unroll
    for (int mi = 0; mi < 4; mi++) {
        #pragma unroll
        for (int ni = 0; ni < 4; ni++) {
            int px = pxbase + ni * 16 + lr;
            int ocb = ocbase + mi * 16 + lq * 4;
            #pragma unroll
            for (int rr = 0; rr < 4; rr++)
                obase[(size_t)(ocb + rr) * 4096 + px] = acc[mi][ni][rr];
        }
    }
}

extern "C" void kernel_launch(void* const* d_in, const int* in_sizes, int n_in,
                              void* d_out, int out_size, void* d_ws, size_t ws_size,
                              hipStream_t stream) {
    const float* x  = (const float*)d_in[0];
    const float* U  = (const float*)d_in[1];
    const float* bp = (const float*)d_in[2];
    const float* uu = (const float*)d_in[3];
    float* out = (float*)d_out;

    char* ws = (char*)d_ws;
    float* part = (float*)ws;                                   // 512 floats
    float* scal = (float*)(ws + 2048);                          // beta, alpha
    unsigned short* Wb2 = (unsigned short*)(ws + 4096);         // 1,769,472 B
    unsigned short* xT  = (unsigned short*)(ws + 4096 + 1769472); // 50,331,648 B

    reduce_part <<<256, 256, 0, stream>>>(U, part);
    reduce_final<<<1, 256, 0, stream>>>(part, scal);
    make_weights<<<576, 256, 0, stream>>>(U, bp, uu, scal, Wb2);
    transform_x <<<48 * 64, 256, 0, stream>>>(x, xT);
    conv_mfma   <<<48 * 32, 256, 0, stream>>>(xT, Wb2, out);
}

// Round 2
// 277.672 us; speedup vs baseline: 1.1295x; 1.1295x over previous
//
#include <hip/hip_runtime.h>
#include <stdint.h>

typedef __attribute__((ext_vector_type(8))) short bf16x8;
typedef __attribute__((ext_vector_type(4))) float f32x4;

#define DW 147456        // per-member weight elems = 128*128*3*3
#define NTOT (6 * DW)    // U elems

__device__ __forceinline__ unsigned short f2bf(float f) {
    unsigned int u = __float_as_uint(f);
    u = (u + 0x7FFFu + ((u >> 16) & 1u)) >> 16;   // RNE, matches XLA f32->bf16
    return (unsigned short)u;
}

// ---------- 1) min/max reduction over U ----------
__global__ __launch_bounds__(256) void reduce_part(const float* __restrict__ U,
                                                   float* __restrict__ part) {
    int tid = threadIdx.x;
    float mx = -INFINITY, mn = INFINITY;
    for (int i = blockIdx.x * 256 + tid; i < NTOT; i += 256 * 256) {
        float v = U[i];
        mx = fmaxf(mx, v);
        mn = fminf(mn, v);
    }
    __shared__ float smx[256], smn[256];
    smx[tid] = mx; smn[tid] = mn;
    __syncthreads();
    for (int s = 128; s > 0; s >>= 1) {
        if (tid < s) {
            smx[tid] = fmaxf(smx[tid], smx[tid + s]);
            smn[tid] = fminf(smn[tid], smn[tid + s]);
        }
        __syncthreads();
    }
    if (tid == 0) { part[blockIdx.x] = smx[0]; part[256 + blockIdx.x] = smn[0]; }
}

__global__ __launch_bounds__(256) void reduce_final(const float* __restrict__ part,
                                                    float* __restrict__ scal) {
    int tid = threadIdx.x;
    __shared__ float smx[256], smn[256];
    smx[tid] = part[tid]; smn[tid] = part[256 + tid];
    __syncthreads();
    for (int s = 128; s > 0; s >>= 1) {
        if (tid < s) {
            smx[tid] = fmaxf(smx[tid], smx[tid + s]);
            smn[tid] = fminf(smn[tid], smn[tid + s]);
        }
        __syncthreads();
    }
    if (tid == 0) { scal[0] = smx[0]; scal[1] = smn[0]; }
}

// ---------- 2) weight synthesis -> bf16, layout [mem][c][tap][oc][32ch] ----------
__global__ __launch_bounds__(256) void make_weights(const float* __restrict__ U,
                                                    const float* __restrict__ bp,
                                                    const float* __restrict__ uu,
                                                    const float* __restrict__ scal,
                                                    unsigned short* __restrict__ Wb2) {
    int d = blockIdx.x * 256 + threadIdx.x;
    if (d >= DW) return;
    float beta = scal[0], alpha = scal[1];
    float s1 = (beta - alpha) / 3.0f;
    float s2 = s1 / 5.0f;

    float v1[6]; float vsum = 0.f;
    #pragma unroll
    for (int n = 0; n < 6; n++) {
        float Un = U[n * DW + d];
        float v = s1 * rintf(Un / s1);   // rintf = round-half-even = jnp.round
        v1[n] = v; vsum += v;
    }
    float vmean = vsum / 6.0f;

    float g6;
    {
        float un = uu[6 * DW + d];
        float g = logf(un / (1.0f - un));
        float sg = 1.0f / (1.0f + expf(-(g + bp[6 * DW + d])));
        g6 = fminf(fmaxf(sg * 1.4f - 0.2f, 0.0f), 1.0f);
    }

    int oc = d / 1152;
    int rem = d - oc * 1152;
    int ic = rem / 9;
    int t9 = rem - ic * 9;
    int c = ic >> 5, icc = ic & 31;
    size_t base = ((size_t)c * 9 + t9) * 4096 + (size_t)oc * 32 + icc;

    #pragma unroll
    for (int n = 0; n < 6; n++) {
        float un = uu[n * DW + d];
        float g = logf(un / (1.0f - un));
        float sg = 1.0f / (1.0f + expf(-(g + bp[n * DW + d])));
        float g0 = fminf(fmaxf(sg * 1.4f - 0.2f, 0.0f), 1.0f);
        float Un = U[n * DW + d];
        float v2 = s2 * rintf((Un - vmean) / s2);
        float w = v1[n] * g0 + ((g0 > 0.0f && g6 > 0.0f) ? v2 * g6 : 0.0f);
        Wb2[(size_t)n * DW + base] = f2bf(w);
    }
}

// ---------- 3) NCHW fp32 -> [img][row][col][ch] bf16 ----------
__global__ __launch_bounds__(256) void transform_x(const float* __restrict__ x,
                                                   unsigned short* __restrict__ xT) {
    __shared__ unsigned short Sh[128 * 70];
    int b = blockIdx.x;
    int img = b >> 6, row = b & 63;
    int tid = threadIdx.x;
    {
        int ch = tid >> 1;
        int col0 = (tid & 1) * 32;
        const float* src = x + (((size_t)(img * 128 + ch) * 64 + row) * 64 + col0);
        #pragma unroll
        for (int j = 0; j < 8; j++) {
            float4 v = ((const float4*)src)[j];
            unsigned int p0 = (unsigned int)f2bf(v.x) | ((unsigned int)f2bf(v.y) << 16);
            unsigned int p1 = (unsigned int)f2bf(v.z) | ((unsigned int)f2bf(v.w) << 16);
            unsigned int* dst = (unsigned int*)&Sh[ch * 70 + col0 + j * 4];
            dst[0] = p0; dst[1] = p1;
        }
    }
    __syncthreads();
    {
        int col = tid & 63;
        int chg = (tid >> 6) * 32;
        union { unsigned short s[32]; uint4 v[4]; } tmp;
        #pragma unroll
        for (int j = 0; j < 32; j++) tmp.s[j] = Sh[(chg + j) * 70 + col];
        uint4* dst = (uint4*)(xT + (((size_t)(img * 64 + row) * 64 + col) * 128 + chg));
        #pragma unroll
        for (int k = 0; k < 4; k++) dst[k] = tmp.v[k];
    }
}

// ---------- 4) grouped conv via implicit-GEMM MFMA ----------
// block: 128 oc x 128 px (2 rows x 64 cols), K = 4 ch-chunks x 9 taps x K32.
// X staged ONCE per chunk as [4 rows][66 cols][32ch]; taps read LDS at
// shifted immediate offsets. W (8KB/tap) double-buffered via global_load_lds.
typedef const __attribute__((address_space(1))) void CGV;
typedef __attribute__((address_space(3))) void LV;

__global__ __launch_bounds__(256) void conv_mfma(const unsigned short* __restrict__ xT,
                                                 const unsigned short* __restrict__ Wb2,
                                                 float* __restrict__ out) {
    __shared__ __align__(16) unsigned short Xs[4 * 66 * 32];   // 16896 B
    __shared__ __align__(16) unsigned short Wd[2][4096];       // 16384 B
    int blk = blockIdx.x;
    int img = blk >> 5;
    int row0 = (blk & 31) * 2;
    int mem = img - (img / 6) * 6;
    const unsigned short* Wsrc = Wb2 + (size_t)mem * DW;
    const unsigned short* Xsrc = xT + (size_t)img * 524288;

    int tid = threadIdx.x;
    int lane = tid & 63;
    int wave = tid >> 6;
    int ocbase = (wave & 1) * 64;
    int prow = wave >> 1;              // which of the 2 output rows this wave handles
    int lr = lane & 15, lq = lane >> 4;

    f32x4 acc[4][4];
    #pragma unroll
    for (int mi = 0; mi < 4; mi++)
        #pragma unroll
        for (int ni = 0; ni < 4; ni++)
            acc[mi][ni] = (f32x4){0.f, 0.f, 0.f, 0.f};

    // async W prefetch: 8KB contiguous = 2 x (256 lanes x 16B)
    auto prefetchW = [&](int it, int buf) {
        const unsigned short* wp = Wsrc + it * 4096;
        #pragma unroll
        for (int k = 0; k < 2; k++) {
            __builtin_amdgcn_global_load_lds((CGV*)(wp + (tid + k * 256) * 8),
                                             (LV*)(&Wd[buf][(tid + k * 256) * 8]),
                                             16, 0, 0);
        }
    };

    // stage X chunk c: [r 0..3][col 0..65][32ch], zero-padded halo
    auto stageX = [&](int c) {
        #pragma unroll
        for (int k = 0; k < 3; k++) {
            int i = tid + k * 256;           // 528 slots x 32B
            if (i < 528) {
                int r = i / 132;
                int rem = i - r * 132;
                int cl = rem >> 1, half = rem & 1;
                int srow = row0 + r - 1;
                int scol = cl - 1;
                uint4 v0 = make_uint4(0u, 0u, 0u, 0u), v1 = v0;
                if ((unsigned)srow < 64u && (unsigned)scol < 64u) {
                    const uint4* p = (const uint4*)(Xsrc + ((srow * 64 + scol) * 128 + c * 32 + half * 16));
                    v0 = p[0]; v1 = p[1];
                }
                uint4* d = (uint4*)(Xs + i * 16);
                d[0] = v0; d[1] = v1;
            }
        }
    };

    prefetchW(0, 0);
    stageX(0);
    __syncthreads();

    #pragma unroll
    for (int c = 0; c < 4; c++) {
        #pragma unroll
        for (int t = 0; t < 9; t++) {
            int it = c * 9 + t;
            if (it + 1 < 36) prefetchW(it + 1, (it + 1) & 1);
            int dy = t / 3, dx = t - dy * 3;
            bf16x8 af[4], bfr[4];
            #pragma unroll
            for (int mi = 0; mi < 4; mi++)
                af[mi] = *(const bf16x8*)(&Wd[it & 1][(ocbase + mi * 16 + lr) * 32 + lq * 8]);
            #pragma unroll
            for (int ni = 0; ni < 4; ni++)
                bfr[ni] = *(const bf16x8*)(Xs + (((prow + dy) * 66 + ni * 16 + lr + dx) * 32 + lq * 8));
            #pragma unroll
            for (int mi = 0; mi < 4; mi++)
                #pragma unroll
                for (int ni = 0; ni < 4; ni++)
                    acc[mi][ni] = __builtin_amdgcn_mfma_f32_16x16x32_bf16(
                        af[mi], bfr[ni], acc[mi][ni], 0, 0, 0);
            __syncthreads();
            if (t == 8 && c < 3) { stageX(c + 1); __syncthreads(); }
        }
    }

    // epilogue: C/D layout col=lane&15 (=px), row=(lane>>4)*4+reg (=oc)
    float* obase = out + (size_t)img * 524288 + row0 * 64;
    #pragma unroll
    for (int mi = 0; mi < 4; mi++) {
        #pragma unroll
        for (int ni = 0; ni < 4; ni++) {
            int px = prow * 64 + ni * 16 + lr;
            int ocb = ocbase + mi * 16 + lq * 4;
            #pragma unroll
            for (int rr = 0; rr < 4; rr++)
                obase[(size_t)(ocb + rr) * 4096 + px] = acc[mi][ni][rr];
        }
    }
}

extern "C" void kernel_launch(void* const* d_in, const int* in_sizes, int n_in,
                              void* d_out, int out_size, void* d_ws, size_t ws_size,
                              hipStream_t stream) {
    const float* x  = (const float*)d_in[0];
    const float* U  = (const float*)d_in[1];
    const float* bp = (const float*)d_in[2];
    const float* uu = (const float*)d_in[3];
    float* out = (float*)d_out;

    char* ws = (char*)d_ws;
    float* part = (float*)ws;                                     // 512 floats
    float* scal = (float*)(ws + 2048);                            // beta, alpha
    unsigned short* Wb2 = (unsigned short*)(ws + 4096);           // 1,769,472 B
    unsigned short* xT  = (unsigned short*)(ws + 4096 + 1769472); // 50,331,648 B

    reduce_part <<<256, 256, 0, stream>>>(U, part);
    reduce_final<<<1, 256, 0, stream>>>(part, scal);
    make_weights<<<576, 256, 0, stream>>>(U, bp, uu, scal, Wb2);
    transform_x <<<48 * 64, 256, 0, stream>>>(x, xT);
    conv_mfma   <<<48 * 32, 256, 0, stream>>>(xT, Wb2, out);
}

// Round 3
// 253.497 us; speedup vs baseline: 1.2372x; 1.0954x over previous
//
#include <hip/hip_runtime.h>
#include <stdint.h>

typedef __attribute__((ext_vector_type(8))) short bf16x8;
typedef __attribute__((ext_vector_type(4))) float f32x4;

#define DW 147456        // per-member weight elems = 128*128*3*3
#define NTOT (6 * DW)    // U elems

__device__ __forceinline__ unsigned short f2bf(float f) {
    unsigned int u = __float_as_uint(f);
    u = (u + 0x7FFFu + ((u >> 16) & 1u)) >> 16;   // RNE, matches XLA f32->bf16
    return (unsigned short)u;
}

// ---------- 1) partial min/max reduction over U (float4) ----------
__global__ __launch_bounds__(256) void reduce_part(const float* __restrict__ U,
                                                   float* __restrict__ part) {
    int tid = threadIdx.x;
    float mx = -INFINITY, mn = INFINITY;
    const float4* U4 = (const float4*)U;
    for (int i = blockIdx.x * 256 + tid; i < NTOT / 4; i += 256 * 256) {
        float4 v = U4[i];
        mx = fmaxf(fmaxf(fmaxf(mx, v.x), v.y), fmaxf(v.z, v.w));
        mn = fminf(fminf(fminf(mn, v.x), v.y), fminf(v.z, v.w));
    }
    __shared__ float smx[256], smn[256];
    smx[tid] = mx; smn[tid] = mn;
    __syncthreads();
    for (int s = 128; s > 0; s >>= 1) {
        if (tid < s) {
            smx[tid] = fmaxf(smx[tid], smx[tid + s]);
            smn[tid] = fminf(smn[tid], smn[tid + s]);
        }
        __syncthreads();
    }
    if (tid == 0) { part[blockIdx.x] = smx[0]; part[256 + blockIdx.x] = smn[0]; }
}

// ---------- 2) weight synthesis (final reduce fused) -> bf16 [mem][c][tap][oc][32ch] ----------
__global__ __launch_bounds__(256) void make_weights(const float* __restrict__ U,
                                                    const float* __restrict__ bp,
                                                    const float* __restrict__ uu,
                                                    const float* __restrict__ part,
                                                    unsigned short* __restrict__ Wb2) {
    int tid = threadIdx.x;
    __shared__ float smx[256], smn[256];
    smx[tid] = part[tid]; smn[tid] = part[256 + tid];
    __syncthreads();
    for (int s = 128; s > 0; s >>= 1) {
        if (tid < s) {
            smx[tid] = fmaxf(smx[tid], smx[tid + s]);
            smn[tid] = fminf(smn[tid], smn[tid + s]);
        }
        __syncthreads();
    }
    float beta = smx[0], alpha = smn[0];
    float s1 = (beta - alpha) / 3.0f;
    float s2 = s1 / 5.0f;

    int d = blockIdx.x * 256 + tid;

    float v1[6]; float Uv[6]; float vsum = 0.f;
    #pragma unroll
    for (int n = 0; n < 6; n++) {
        float Un = U[n * DW + d];
        Uv[n] = Un;
        float v = s1 * rintf(Un / s1);   // rintf = round-half-even = jnp.round
        v1[n] = v; vsum += v;
    }
    float vmean = vsum / 6.0f;

    // sigmoid(log(u/(1-u)) + b) == u / (u + (1-u)*exp(-b))  (saves the logf)
    float g6;
    {
        float un = uu[6 * DW + d];
        float sg = un / (un + (1.0f - un) * expf(-bp[6 * DW + d]));
        g6 = fminf(fmaxf(sg * 1.4f - 0.2f, 0.0f), 1.0f);
    }

    int oc = d / 1152;
    int rem = d - oc * 1152;
    int ic = rem / 9;
    int t9 = rem - ic * 9;
    int c = ic >> 5, icc = ic & 31;
    size_t base = ((size_t)c * 9 + t9) * 4096 + (size_t)oc * 32 + icc;

    #pragma unroll
    for (int n = 0; n < 6; n++) {
        float un = uu[n * DW + d];
        float sg = un / (un + (1.0f - un) * expf(-bp[n * DW + d]));
        float g0 = fminf(fmaxf(sg * 1.4f - 0.2f, 0.0f), 1.0f);
        float v2 = s2 * rintf((Uv[n] - vmean) / s2);
        float w = v1[n] * g0 + ((g0 > 0.0f && g6 > 0.0f) ? v2 * g6 : 0.0f);
        Wb2[(size_t)n * DW + base] = f2bf(w);
    }
}

// ---------- 3) NCHW fp32 -> [img][c(4)][row][col][32ch] bf16 (chunk-major) ----------
__global__ __launch_bounds__(256) void transform_x(const float* __restrict__ x,
                                                   unsigned short* __restrict__ xT) {
    __shared__ unsigned short Sh[128 * 70];
    int b = blockIdx.x;
    int img = b >> 6, row = b & 63;
    int tid = threadIdx.x;
    {
        int ch = tid >> 1;
        int col0 = (tid & 1) * 32;
        const float* src = x + (((size_t)(img * 128 + ch) * 64 + row) * 64 + col0);
        #pragma unroll
        for (int j = 0; j < 8; j++) {
            float4 v = ((const float4*)src)[j];
            unsigned int p0 = (unsigned int)f2bf(v.x) | ((unsigned int)f2bf(v.y) << 16);
            unsigned int p1 = (unsigned int)f2bf(v.z) | ((unsigned int)f2bf(v.w) << 16);
            unsigned int* dst = (unsigned int*)&Sh[ch * 70 + col0 + j * 4];
            dst[0] = p0; dst[1] = p1;
        }
    }
    __syncthreads();
    {
        int col = tid & 63;
        int q = tid >> 6;            // chunk = wave index
        int chg = q * 32;
        union { unsigned short s[32]; uint4 v[4]; } tmp;
        #pragma unroll
        for (int j = 0; j < 32; j++) tmp.s[j] = Sh[(chg + j) * 70 + col];
        // [img][q][row][col][32]
        uint4* dst = (uint4*)(xT + ((size_t)img * 524288 + (size_t)q * 131072 +
                                    (size_t)row * 2048 + col * 32));
        #pragma unroll
        for (int k = 0; k < 4; k++) dst[k] = tmp.v[k];
    }
}

// ---------- 4) grouped conv: 64 oc x 256 px (4 rows) per block ----------
// Per ch-chunk: stage ALL 9 W taps (36KB) + 6 X halo rows (25KB) with
// global_load_lds, ONE barrier pair, then 144 MFMA/wave. 8 barriers total.
typedef const __attribute__((address_space(1))) void CGV;
typedef __attribute__((address_space(3))) void LV;

__global__ __launch_bounds__(256) void conv_mfma(const unsigned short* __restrict__ xT,
                                                 const unsigned short* __restrict__ Wb2,
                                                 float* __restrict__ out) {
    __shared__ __align__(16) unsigned short Xs[6 * 66 * 32];   // 25344 B
    __shared__ __align__(16) unsigned short Ws[9 * 64 * 32];   // 36864 B
    int blk = blockIdx.x;
    int band = blk & 15;            // 16 bands of 4 output rows
    int och = (blk >> 4) & 1;       // oc half
    int img = blk >> 5;
    int row0 = band * 4;
    int mem = img - (img / 6) * 6;
    const unsigned short* Wsrc = Wb2 + (size_t)mem * DW + och * 2048;
    const unsigned short* Xsrc = xT + (size_t)img * 524288;

    int tid = threadIdx.x;
    int lane = tid & 63;
    int prow = tid >> 6;            // wave = one of 4 output rows
    int lr = lane & 15, lq = lane >> 4;

    // zero the halo border columns (col 0 and 65) once; never overwritten
    if (tid < 192) {
        int r = tid >> 5, j = tid & 31;
        int col = (j < 16) ? 0 : 65;
        *(unsigned int*)&Xs[(r * 66 + col) * 32 + (j & 15) * 2] = 0u;
    }

    auto stage = [&](int c) {
        // W: 9 taps x 4KB, each contiguous ([c][t][oc128][32], och half)
        #pragma unroll
        for (int t = 0; t < 9; t++)
            __builtin_amdgcn_global_load_lds((CGV*)(Wsrc + (c * 9 + t) * 4096 + tid * 8),
                                             (LV*)(&Ws[t * 2048 + tid * 8]), 16, 0, 0);
        // X: 6 halo rows x 4KB contiguous (chunk-major layout)
        #pragma unroll
        for (int r = 0; r < 6; r++) {
            int srow = row0 + r - 1;
            if ((unsigned)srow < 64u)
                __builtin_amdgcn_global_load_lds((CGV*)(Xsrc + c * 131072 + srow * 2048 + tid * 8),
                                                 (LV*)(&Xs[(r * 66 + 1) * 32 + tid * 8]), 16, 0, 0);
            else
                *(uint4*)&Xs[(r * 66 + 1) * 32 + tid * 8] = make_uint4(0u, 0u, 0u, 0u);
        }
    };

    f32x4 acc[4][4];
    #pragma unroll
    for (int mi = 0; mi < 4; mi++)
        #pragma unroll
        for (int ni = 0; ni < 4; ni++)
            acc[mi][ni] = (f32x4){0.f, 0.f, 0.f, 0.f};

    stage(0);
    __syncthreads();

    for (int c = 0; c < 4; c++) {
        #pragma unroll
        for (int t = 0; t < 9; t++) {
            int dy = t / 3, dx = t - dy * 3;
            bf16x8 af[4], bfr[4];
            #pragma unroll
            for (int mi = 0; mi < 4; mi++)
                af[mi] = *(const bf16x8*)(&Ws[t * 2048 + (mi * 16 + lr) * 32 + lq * 8]);
            #pragma unroll
            for (int ni = 0; ni < 4; ni++)
                bfr[ni] = *(const bf16x8*)(&Xs[((prow + dy) * 66 + ni * 16 + lr + dx) * 32 + lq * 8]);
            #pragma unroll
            for (int mi = 0; mi < 4; mi++)
                #pragma unroll
                for (int ni = 0; ni < 4; ni++)
                    acc[mi][ni] = __builtin_amdgcn_mfma_f32_16x16x32_bf16(
                        af[mi], bfr[ni], acc[mi][ni], 0, 0, 0);
        }
        if (c < 3) {
            __syncthreads();     // all waves done with Xs/Ws
            stage(c + 1);
            __syncthreads();     // staging landed (compiler drains vmcnt)
        }
    }

    // epilogue: C/D layout col=lane&15 (=px col), row=lq*4+reg (=oc)
    float* obase = out + (size_t)img * 524288 + (size_t)(row0 + prow) * 64;
    #pragma unroll
    for (int mi = 0; mi < 4; mi++) {
        #pragma unroll
        for (int ni = 0; ni < 4; ni++) {
            int px = ni * 16 + lr;
            int ocb = och * 64 + mi * 16 + lq * 4;
            #pragma unroll
            for (int rr = 0; rr < 4; rr++)
                obase[(size_t)(ocb + rr) * 4096 + px] = acc[mi][ni][rr];
        }
    }
}

extern "C" void kernel_launch(void* const* d_in, const int* in_sizes, int n_in,
                              void* d_out, int out_size, void* d_ws, size_t ws_size,
                              hipStream_t stream) {
    const float* x  = (const float*)d_in[0];
    const float* U  = (const float*)d_in[1];
    const float* bp = (const float*)d_in[2];
    const float* uu = (const float*)d_in[3];
    float* out = (float*)d_out;

    char* ws = (char*)d_ws;
    float* part = (float*)ws;                                     // 512 floats
    unsigned short* Wb2 = (unsigned short*)(ws + 4096);           // 1,769,472 B
    unsigned short* xT  = (unsigned short*)(ws + 4096 + 1769472); // 50,331,648 B

    reduce_part <<<256, 256, 0, stream>>>(U, part);
    make_weights<<<576, 256, 0, stream>>>(U, bp, uu, part, Wb2);
    transform_x <<<48 * 64, 256, 0, stream>>>(x, xT);
    conv_mfma   <<<48 * 32, 256, 0, stream>>>(xT, Wb2, out);
}